// Round 4
// baseline (673.214 us; speedup 1.0000x reference)
//
#include <hip/hip_runtime.h>
#include <hip/hip_bf16.h>

#define T_TOT 512
#define NB    128      // batch
#define NI    128      // n_inp
#define NH    1024     // n_hid
#define NJ    2048     // n_hid * n_ch

typedef __attribute__((ext_vector_type(8))) short short8;
typedef __attribute__((ext_vector_type(4))) float f32x4;

__device__ __forceinline__ short f2bf_s(float f) {
  __hip_bfloat16 h = __float2bfloat16(f);
  short s; __builtin_memcpy(&s, &h, 2); return s;
}
__device__ __forceinline__ unsigned short f2bf_u(float f) {
  __hip_bfloat16 h = __float2bfloat16(f);
  unsigned short s; __builtin_memcpy(&s, &h, 2); return s;
}
__device__ __forceinline__ float bf2f(unsigned short u) {
  unsigned v = ((unsigned)u) << 16; float f; __builtin_memcpy(&f, &v, 4); return f;
}
__device__ __forceinline__ float fast_tanh(float x) {
  float e = __expf(2.0f * x);
  return 1.0f - __fdividef(2.0f, e + 1.0f);   // exact at +-inf, abs err ~1e-7
}

// ---- kernel 1: split Wx_w (f32 [2048][128]) into hi/lo bf16 ----
__global__ void cvt_wx(const float* __restrict__ w,
                       unsigned short* __restrict__ hi,
                       unsigned short* __restrict__ lo) {
  int i = blockIdx.x * blockDim.x + threadIdx.x;
  for (int k = i; k < NJ * NI; k += gridDim.x * blockDim.x) {
    float f = w[k];
    unsigned short h = f2bf_u(f);
    hi[k] = h;
    lo[k] = f2bf_u(f - bf2f(h));
  }
}

#define MFMA __builtin_amdgcn_mfma_f32_16x16x32_bf16

// ---- kernel 2: U[m][j] = sum_i x[m][i]*W[j][i] + b[j] (fp32 out, split-bf16) ----
// Operand-swapped: D = W_strip(16j x k) * x^T(k x 16m) so each lane's 4 acc
// values are 4 CONSECUTIVE j -> one dwordx4 store per acc.
// grid = (T_c, 4): blockIdx.x = timestep (128 rows), blockIdx.y = 512-col quarter.
__global__ __launch_bounds__(256) void gemm_u(
    const float* __restrict__ x,            // chunk base, [T_c*128][128] f32
    const unsigned short* __restrict__ Whi, // [2048][128] bf16 (L2/L3-resident)
    const unsigned short* __restrict__ Wlo, // [2048][128] bf16
    const float* __restrict__ Wxb,          // [2048]
    float* __restrict__ U)                  // [T_c*128][2048] f32
{
  const int l  = threadIdx.x & 63;
  const int lr = l & 15;   // x-row / W-row within 16
  const int lk = l >> 4;   // k-group (8 contiguous k per lane)
  const long m0 = (long)blockIdx.x * 128 + (threadIdx.x >> 6) * 32;
  const int jb = blockIdx.y * (NJ / 4);

  // x fragments (MFMA "B" operand): lane holds x[m0 + ms*16 + lr][lk*8 + e]
  short8 xh[2][4], xl[2][4];
  #pragma unroll
  for (int ms = 0; ms < 2; ++ms) {
    const float* xr = x + (m0 + ms * 16 + lr) * NI + lk * 8;
    #pragma unroll
    for (int kk = 0; kk < 4; ++kk) {
      float4 p = *(const float4*)(xr + kk * 32);
      float4 q = *(const float4*)(xr + kk * 32 + 4);
      float f[8] = {p.x, p.y, p.z, p.w, q.x, q.y, q.z, q.w};
      short8 vh, vl;
      #pragma unroll
      for (int e = 0; e < 8; ++e) {
        unsigned short h = f2bf_u(f[e]);
        vh[e] = (short)h;
        vl[e] = f2bf_s(f[e] - bf2f(h));
      }
      xh[ms][kk] = vh;
      xl[ms][kk] = vl;
    }
  }

#define LOADW(WH, WL, J0) do {                                                \
    const size_t wo = (size_t)((J0) + lr) * NI + lk * 8;                      \
    WH[0] = *(const short8*)(Whi + wo);       WH[1] = *(const short8*)(Whi + wo + 32); \
    WH[2] = *(const short8*)(Whi + wo + 64);  WH[3] = *(const short8*)(Whi + wo + 96); \
    WL[0] = *(const short8*)(Wlo + wo);       WL[1] = *(const short8*)(Wlo + wo + 32); \
    WL[2] = *(const short8*)(Wlo + wo + 64);  WL[3] = *(const short8*)(Wlo + wo + 96); \
  } while (0)

#define COMPUTE(WH, WL, J0) do {                                              \
    f32x4 acc0 = {0.f, 0.f, 0.f, 0.f};                                        \
    f32x4 acc1 = {0.f, 0.f, 0.f, 0.f};                                        \
    _Pragma("unroll")                                                         \
    for (int kk = 0; kk < 4; ++kk) {                                          \
      acc0 = MFMA(WH[kk], xh[0][kk], acc0, 0, 0, 0);                          \
      acc0 = MFMA(WH[kk], xl[0][kk], acc0, 0, 0, 0);                          \
      acc0 = MFMA(WL[kk], xh[0][kk], acc0, 0, 0, 0);                          \
      acc1 = MFMA(WH[kk], xh[1][kk], acc1, 0, 0, 0);                          \
      acc1 = MFMA(WH[kk], xl[1][kk], acc1, 0, 0, 0);                          \
      acc1 = MFMA(WL[kk], xh[1][kk], acc1, 0, 0, 0);                          \
    }                                                                         \
    const float4 b4 = *(const float4*)(Wxb + (J0) + lk * 4);                  \
    /* D layout: col(lane&15)=m within half, row(lk*4+r)=j offset */          \
    float4 o0 = make_float4(acc0[0] + b4.x, acc0[1] + b4.y, acc0[2] + b4.z, acc0[3] + b4.w); \
    float4 o1 = make_float4(acc1[0] + b4.x, acc1[1] + b4.y, acc1[2] + b4.z, acc1[3] + b4.w); \
    *(float4*)(U + (m0 + lr) * NJ + (J0) + lk * 4)        = o0;               \
    *(float4*)(U + (m0 + 16 + lr) * NJ + (J0) + lk * 4)   = o1;               \
  } while (0)

  short8 whA[4], wlA[4], whB[4], wlB[4];
  LOADW(whA, wlA, jb);
  for (int s = 0; s < 32; s += 2) {
    const int j0 = jb + s * 16;
    LOADW(whB, wlB, j0 + 16);                 // prefetch strip s+1
    COMPUTE(whA, wlA, j0);
    if (s + 2 < 32) LOADW(whA, wlA, j0 + 32); // prefetch strip s+2
    COMPUTE(whB, wlB, j0 + 16);
  }
#undef LOADW
#undef COMPUTE
}

// ---- kernel 3: recurrence. 256 thr/block, 4 hidden idx/thread, shuffle halo,
// raw s_barrier (NO vmcnt drain) so 8-deep U prefetch streams across steps ----
__global__ __launch_bounds__(256) void recur(
    const float* __restrict__ U,            // chunk [T_c][128][2048] f32
    const float* __restrict__ Wyw,          // [2][2][1024][3]
    const float* __restrict__ Wyb,          // [2][1024]
    const float* __restrict__ Rw,           // [10][2048]
    const float* __restrict__ Rb,           // [10]
    float* __restrict__ state,              // [128][2048] carry between chunks
    float* __restrict__ out,                // [128][10]
    int T_c, int flags)                     // bit0 = first chunk, bit1 = last chunk
{
  const int b    = blockIdx.x;
  const int tid  = threadIdx.x;
  const int lane = tid & 63;
  const int wv   = tid >> 6;
  const int n0   = tid * 4;
  __shared__ float edge[2][2][4][2];        // [parity][L=0/R=1][wave][ch]
  __shared__ float red[4][10];

  // conv weights (registers, constant-indexed after unroll): W[o][c][m][k]
  float W00[12], W01[12], W10[12], W11[12];
  {
    const size_t o00 = (size_t)n0 * 3;
    const size_t o01 = (size_t)(NH + n0) * 3;
    const size_t o10 = (size_t)(2 * NH + n0) * 3;
    const size_t o11 = (size_t)(3 * NH + n0) * 3;
    *(float4*)&W00[0] = *(const float4*)(Wyw + o00);
    *(float4*)&W00[4] = *(const float4*)(Wyw + o00 + 4);
    *(float4*)&W00[8] = *(const float4*)(Wyw + o00 + 8);
    *(float4*)&W01[0] = *(const float4*)(Wyw + o01);
    *(float4*)&W01[4] = *(const float4*)(Wyw + o01 + 4);
    *(float4*)&W01[8] = *(const float4*)(Wyw + o01 + 8);
    *(float4*)&W10[0] = *(const float4*)(Wyw + o10);
    *(float4*)&W10[4] = *(const float4*)(Wyw + o10 + 4);
    *(float4*)&W10[8] = *(const float4*)(Wyw + o10 + 8);
    *(float4*)&W11[0] = *(const float4*)(Wyw + o11);
    *(float4*)&W11[4] = *(const float4*)(Wyw + o11 + 4);
    *(float4*)&W11[8] = *(const float4*)(Wyw + o11 + 8);
  }
  const float4 B0 = *(const float4*)(Wyb + n0);
  const float4 B1 = *(const float4*)(Wyb + NH + n0);
  const float B0a[4] = {B0.x, B0.y, B0.z, B0.w};
  const float B1a[4] = {B1.x, B1.y, B1.z, B1.w};

  float y0[4], y1[4];   // own state, register-carried
  if (flags & 1) {
    #pragma unroll
    for (int j = 0; j < 4; ++j) { y0[j] = 0.f; y1[j] = 0.f; }
  } else {
    float4 s0 = *(const float4*)(state + (size_t)b * NJ + n0);
    float4 s1 = *(const float4*)(state + (size_t)b * NJ + NH + n0);
    y0[0]=s0.x; y0[1]=s0.y; y0[2]=s0.z; y0[3]=s0.w;
    y1[0]=s1.x; y1[1]=s1.y; y1[2]=s1.z; y1[3]=s1.w;
  }

  float lv0, lv1, rv0, rv1;   // halo: h[n0-1] and h[n0+4], both channels

  // Exchange: intra-wave via shfl; wave boundaries via 16 floats of LDS.
  // Raw barrier (lgkmcnt only) -> global-load prefetch stays in flight.
#define EXCH(P) do {                                                          \
    if (lane == 0)  { edge[P][0][wv][0] = y0[0]; edge[P][0][wv][1] = y1[0]; } \
    if (lane == 63) { edge[P][1][wv][0] = y0[3]; edge[P][1][wv][1] = y1[3]; } \
    lv0 = __shfl(y0[3], (lane + 63) & 63);                                    \
    lv1 = __shfl(y1[3], (lane + 63) & 63);                                    \
    rv0 = __shfl(y0[0], (lane + 1) & 63);                                     \
    rv1 = __shfl(y1[0], (lane + 1) & 63);                                     \
    asm volatile("s_waitcnt lgkmcnt(0)" ::: "memory");                        \
    __builtin_amdgcn_s_barrier();                                             \
    if (lane == 0)  { lv0 = edge[P][1][(wv + 3) & 3][0]; lv1 = edge[P][1][(wv + 3) & 3][1]; } \
    if (lane == 63) { rv0 = edge[P][0][(wv + 1) & 3][0]; rv1 = edge[P][0][(wv + 1) & 3][1]; } \
  } while (0)

#define STEP(P, U0V, U1V) do {                                                \
    float h0[6], h1[6];                                                       \
    h0[0]=lv0; h0[1]=y0[0]; h0[2]=y0[1]; h0[3]=y0[2]; h0[4]=y0[3]; h0[5]=rv0; \
    h1[0]=lv1; h1[1]=y1[0]; h1[2]=y1[1]; h1[3]=y1[2]; h1[4]=y1[3]; h1[5]=rv1; \
    const float u0a[4] = {(U0V).x, (U0V).y, (U0V).z, (U0V).w};                \
    const float u1a[4] = {(U1V).x, (U1V).y, (U1V).z, (U1V).w};                \
    _Pragma("unroll")                                                         \
    for (int j = 0; j < 4; ++j) {                                             \
      float loc0 = B0a[j] + W00[j*3]*h0[j] + W00[j*3+1]*h0[j+1] + W00[j*3+2]*h0[j+2] \
                          + W01[j*3]*h1[j] + W01[j*3+1]*h1[j+1] + W01[j*3+2]*h1[j+2]; \
      float loc1 = B1a[j] + W10[j*3]*h0[j] + W10[j*3+1]*h0[j+1] + W10[j*3+2]*h0[j+2] \
                          + W11[j*3]*h1[j] + W11[j*3+1]*h1[j+1] + W11[j*3+2]*h1[j+2]; \
      y0[j] = fast_tanh(u0a[j] + loc0);                                       \
      y1[j] = fast_tanh(u1a[j] + loc1);                                       \
    }                                                                         \
    EXCH(P);                                                                  \
  } while (0)

  EXCH(1);   // initial halo of the starting state

  const float* Ub = U + (size_t)b * NJ + n0;
#define LD(S, T) do { const size_t o = (size_t)(T) * ((size_t)NB * NJ);       \
    S##0 = *(const float4*)(Ub + o); S##1 = *(const float4*)(Ub + o + NH); } while (0)

  // 8-deep prefetch, explicit slots (T_c is a multiple of 8, >= 8)
  float4 pA0,pA1,pB0,pB1,pC0,pC1,pD0,pD1,pE0,pE1,pF0,pF1,pG0,pG1,pH0,pH1;
  LD(pA,0); LD(pB,1); LD(pC,2); LD(pD,3); LD(pE,4); LD(pF,5); LD(pG,6); LD(pH,7);

  for (int t = 0; t < T_c; t += 8) {
    STEP(0, pA0, pA1); if (t +  8 < T_c) LD(pA, t +  8);
    STEP(1, pB0, pB1); if (t +  9 < T_c) LD(pB, t +  9);
    STEP(0, pC0, pC1); if (t + 10 < T_c) LD(pC, t + 10);
    STEP(1, pD0, pD1); if (t + 11 < T_c) LD(pD, t + 11);
    STEP(0, pE0, pE1); if (t + 12 < T_c) LD(pE, t + 12);
    STEP(1, pF0, pF1); if (t + 13 < T_c) LD(pF, t + 13);
    STEP(0, pG0, pG1); if (t + 14 < T_c) LD(pG, t + 14);
    STEP(1, pH0, pH1); if (t + 15 < T_c) LD(pH, t + 15);
  }
#undef LD
#undef STEP
#undef EXCH

  if (flags & 2) {
    // out[b][r] = sum_j hy[b][j] * Rw[r][j] + Rb[r]
    float p[10];
    #pragma unroll
    for (int r = 0; r < 10; ++r) {
      float4 ra = *(const float4*)(Rw + (size_t)r * NJ + n0);
      float4 rb = *(const float4*)(Rw + (size_t)r * NJ + NH + n0);
      p[r] = y0[0]*ra.x + y0[1]*ra.y + y0[2]*ra.z + y0[3]*ra.w
           + y1[0]*rb.x + y1[1]*rb.y + y1[2]*rb.z + y1[3]*rb.w;
    }
    #pragma unroll
    for (int r = 0; r < 10; ++r) {
      #pragma unroll
      for (int off = 32; off > 0; off >>= 1)
        p[r] += __shfl_down(p[r], off);
    }
    __syncthreads();
    if (lane == 0) {
      #pragma unroll
      for (int r = 0; r < 10; ++r) red[wv][r] = p[r];
    }
    __syncthreads();
    if (tid < 10) {
      out[b * 10 + tid] = red[0][tid] + red[1][tid] + red[2][tid] + red[3][tid] + Rb[tid];
    }
  } else {
    *(float4*)(state + (size_t)b * NJ + n0)      = make_float4(y0[0], y0[1], y0[2], y0[3]);
    *(float4*)(state + (size_t)b * NJ + NH + n0) = make_float4(y1[0], y1[1], y1[2], y1[3]);
  }
}

// ---- fallback (only if ws_size is tiny): fully fused slow path ----
__global__ __launch_bounds__(1024) void recur_fb(
    const float* __restrict__ x,
    const float* __restrict__ Wxw, const float* __restrict__ Wxb,
    const float* __restrict__ Wyw, const float* __restrict__ Wyb,
    const float* __restrict__ Rw,  const float* __restrict__ Rb,
    float* __restrict__ out)
{
  const int b = blockIdx.x;
  const int n = threadIdx.x;
  __shared__ float2 h2[2][NH];
  __shared__ float  xs[NI];
  __shared__ float  red[16][10];

  const float w000 = Wyw[(size_t)n*3+0],        w001 = Wyw[(size_t)n*3+1],        w002 = Wyw[(size_t)n*3+2];
  const float w010 = Wyw[(size_t)(NH+n)*3+0],   w011 = Wyw[(size_t)(NH+n)*3+1],   w012 = Wyw[(size_t)(NH+n)*3+2];
  const float w100 = Wyw[(size_t)(2*NH+n)*3+0], w101 = Wyw[(size_t)(2*NH+n)*3+1], w102 = Wyw[(size_t)(2*NH+n)*3+2];
  const float w110 = Wyw[(size_t)(3*NH+n)*3+0], w111 = Wyw[(size_t)(3*NH+n)*3+1], w112 = Wyw[(size_t)(3*NH+n)*3+2];
  const float bias0 = Wyb[n], bias1 = Wyb[NH + n];
  const int nm1 = (n + NH - 1) & (NH - 1);
  const int np1 = (n + 1) & (NH - 1);

  float c0 = 0.f, c1 = 0.f;
  h2[0][n] = make_float2(c0, c1);
  __syncthreads();

  int cur = 0;
  for (int t = 0; t < T_TOT; ++t) {
    if (n < NI) xs[n] = x[(size_t)t * NB * NI + (size_t)b * NI + n];
    __syncthreads();
    float u0 = Wxb[n], u1 = Wxb[NH + n];
    const float* wr0 = Wxw + (size_t)n * NI;
    const float* wr1 = Wxw + (size_t)(NH + n) * NI;
    #pragma unroll 8
    for (int i = 0; i < NI; ++i) {
      u0 = fmaf(xs[i], wr0[i], u0);
      u1 = fmaf(xs[i], wr1[i], u1);
    }
    float2 Lv = h2[cur][nm1];
    float2 Rv = h2[cur][np1];
    float loc0 = bias0 + w000*Lv.x + w001*c0 + w002*Rv.x + w010*Lv.y + w011*c1 + w012*Rv.y;
    float loc1 = bias1 + w100*Lv.x + w101*c0 + w102*Rv.x + w110*Lv.y + w111*c1 + w112*Rv.y;
    c0 = fast_tanh(u0 + loc0);
    c1 = fast_tanh(u1 + loc1);
    h2[cur ^ 1][n] = make_float2(c0, c1);
    cur ^= 1;
    __syncthreads();
  }

  float p[10];
  #pragma unroll
  for (int r = 0; r < 10; ++r)
    p[r] = c0 * Rw[(size_t)r * NJ + n] + c1 * Rw[(size_t)r * NJ + NH + n];
  #pragma unroll
  for (int r = 0; r < 10; ++r) {
    #pragma unroll
    for (int off = 32; off > 0; off >>= 1)
      p[r] += __shfl_down(p[r], off);
  }
  const int wv = n >> 6;
  if ((n & 63) == 0) {
    #pragma unroll
    for (int r = 0; r < 10; ++r) red[wv][r] = p[r];
  }
  __syncthreads();
  if (n < 10) {
    float s = 0.f;
    #pragma unroll
    for (int k = 0; k < 16; ++k) s += red[k][n];
    out[b * 10 + n] = s + Rb[n];
  }
}

extern "C" void kernel_launch(void* const* d_in, const int* in_sizes, int n_in,
                              void* d_out, int out_size, void* d_ws, size_t ws_size,
                              hipStream_t stream) {
  const float* x   = (const float*)d_in[0];
  const float* Wxw = (const float*)d_in[1];
  const float* Wxb = (const float*)d_in[2];
  const float* Wyw = (const float*)d_in[3];
  const float* Wyb = (const float*)d_in[4];
  const float* Rw  = (const float*)d_in[5];
  const float* Rb  = (const float*)d_in[6];
  float* out = (float*)d_out;

  const size_t w1_bytes = (size_t)NJ * NI * 2;       // 512 KB bf16 Wx (hi)
  const size_t wb_bytes = 2 * w1_bytes;              // hi + lo
  const size_t st_bytes = (size_t)NB * NJ * 4;       // 1 MB carry state
  const size_t ut_bytes = (size_t)NB * NJ * 4;       // 1 MB per timestep of U (fp32)
  unsigned short* Whi = (unsigned short*)d_ws;
  unsigned short* Wlo = (unsigned short*)((char*)d_ws + w1_bytes);
  float* state = (float*)((char*)d_ws + wb_bytes);
  float* U = (float*)((char*)d_ws + wb_bytes + st_bytes);

  long Tc = 0;
  if (ws_size > wb_bytes + st_bytes)
    Tc = (long)((ws_size - wb_bytes - st_bytes) / ut_bytes);
  if (Tc > T_TOT) Tc = T_TOT;
  Tc &= ~7L;   // chunks multiple of 8 (recur prefetch depth)

  if (Tc >= 8) {
    cvt_wx<<<64, 256, 0, stream>>>(Wxw, Whi, Wlo);
    for (int t0 = 0; t0 < T_TOT; t0 += (int)Tc) {
      int tc = (int)Tc; if (t0 + tc > T_TOT) tc = T_TOT - t0;
      gemm_u<<<dim3(tc, 4), 256, 0, stream>>>(x + (size_t)t0 * NB * NI, Whi, Wlo, Wxb, U);
      const int flags = (t0 == 0 ? 1 : 0) | (t0 + tc >= T_TOT ? 2 : 0);
      recur<<<NB, 256, 0, stream>>>(U, Wyw, Wyb, Rw, Rb, state, out, tc, flags);
    }
  } else {
    recur_fb<<<NB, 1024, 0, stream>>>(x, Wxw, Wxb, Wyw, Wyb, Rw, Rb, out);
  }
}

// Round 5
// 410.897 us; speedup vs baseline: 1.6384x; 1.6384x over previous
//
#include <hip/hip_runtime.h>
#include <hip/hip_bf16.h>

#define T_TOT 512
#define NB    128      // batch
#define NI    128      // n_inp
#define NH    1024     // n_hid
#define NJ    2048     // n_hid * n_ch

typedef __attribute__((ext_vector_type(8))) short short8;
typedef __attribute__((ext_vector_type(4))) float f32x4;
typedef __attribute__((ext_vector_type(2))) float f32x2;

__device__ __forceinline__ unsigned short f2bf_u(float f) {
  __hip_bfloat16 h = __float2bfloat16(f);
  unsigned short s; __builtin_memcpy(&s, &h, 2); return s;
}
__device__ __forceinline__ float bf2f(unsigned short u) {
  unsigned v = ((unsigned)u) << 16; float f; __builtin_memcpy(&f, &v, 4); return f;
}

// ---- split Wx_w (f32 [2048][128]) into hi/lo bf16 ----
__global__ void cvt_wx(const float* __restrict__ w,
                       unsigned short* __restrict__ hi,
                       unsigned short* __restrict__ lo) {
  int i = blockIdx.x * blockDim.x + threadIdx.x;
  for (int k = i; k < NJ * NI; k += gridDim.x * blockDim.x) {
    float f = w[k];
    unsigned short h = f2bf_u(f);
    hi[k] = h;
    lo[k] = f2bf_u(f - bf2f(h));
  }
}

// ---- split x (f32 [T*NB*NI]) into hi/lo bf16 (done once) ----
__global__ void cvt_x(const float* __restrict__ x,
                      unsigned short* __restrict__ hi,
                      unsigned short* __restrict__ lo) {
  const int n = T_TOT * NB * NI;
  int i = blockIdx.x * blockDim.x + threadIdx.x;
  for (int k = i; k < n; k += gridDim.x * blockDim.x) {
    float f = x[k];
    unsigned short h = f2bf_u(f);
    hi[k] = h;
    lo[k] = f2bf_u(f - bf2f(h));
  }
}

#define MFMA __builtin_amdgcn_mfma_f32_16x16x32_bf16

// =====================================================================
// Fused kernel: blocks [0, nrec) run the sequential recurrence for chunk i;
// blocks [nrec, nrec+ngemm) run the U-GEMM for chunk i+1. The two groups
// touch disjoint U halves, so they run concurrently on disjoint CUs.
// =====================================================================
__global__ __launch_bounds__(256) void fused(
    const unsigned short* __restrict__ xhi,  // chunk-offset x hi [Tc*128][128]
    const unsigned short* __restrict__ xlo,
    const unsigned short* __restrict__ Whi,  // [2048][128]
    const unsigned short* __restrict__ Wlo,
    const float* __restrict__ Wxb,           // [2048]
    float* __restrict__ Uw,                  // U half to WRITE (chunk i+1)
    const float* __restrict__ Ur,            // U half to READ  (chunk i)
    const float* __restrict__ Wyw,           // [2][2][1024][3]
    const float* __restrict__ Wyb,           // [2][1024]
    const float* __restrict__ Rw,            // [10][2048]
    const float* __restrict__ Rb,            // [10]
    float* __restrict__ state,               // [128][2048]
    float* __restrict__ out,                 // [128][10]
    int T_c, int nrec, int flags)            // bit0 first chunk, bit1 last chunk
{
  __shared__ float edge[2][2][4][2];         // [parity][L/R][wave][ch]
  __shared__ float red[4][10];

  if ((int)blockIdx.x < nrec) {
    // ================= recurrence (chunk i) =================
    __builtin_amdgcn_s_setprio(1);
    const int b    = blockIdx.x;
    const int tid  = threadIdx.x;
    const int lane = tid & 63;
    const int wv   = tid >> 6;
    const int n0   = tid * 4;

    // channel-paired conv weights: WP0[j*3+k] = {W[0][0], W[1][0]},
    // WP1 = {W[0][1], W[1][1]} -> v_pk_fma_f32 on {loc0, loc1}
    f32x2 WP0[12], WP1[12], BP[4];
    {
      const float* w00 = Wyw + (size_t)n0 * 3;
      const float* w01 = Wyw + (size_t)(NH + n0) * 3;
      const float* w10 = Wyw + (size_t)(2 * NH + n0) * 3;
      const float* w11 = Wyw + (size_t)(3 * NH + n0) * 3;
      #pragma unroll
      for (int i = 0; i < 12; ++i) {
        f32x2 a = {w00[i], w10[i]}; WP0[i] = a;
        f32x2 c = {w01[i], w11[i]}; WP1[i] = c;
      }
      #pragma unroll
      for (int j = 0; j < 4; ++j) { f32x2 bb = {Wyb[n0 + j], Wyb[NH + n0 + j]}; BP[j] = bb; }
    }

    float y0[4], y1[4];
    if (flags & 1) {
      #pragma unroll
      for (int j = 0; j < 4; ++j) { y0[j] = 0.f; y1[j] = 0.f; }
    } else {
      float4 s0 = *(const float4*)(state + (size_t)b * NJ + n0);
      float4 s1 = *(const float4*)(state + (size_t)b * NJ + NH + n0);
      y0[0]=s0.x; y0[1]=s0.y; y0[2]=s0.z; y0[3]=s0.w;
      y1[0]=s1.x; y1[1]=s1.y; y1[2]=s1.z; y1[3]=s1.w;
    }

    float lv0, lv1, rv0, rv1;

#define EXCH(P) do {                                                          \
    if (lane == 0)  { edge[P][0][wv][0] = y0[0]; edge[P][0][wv][1] = y1[0]; } \
    if (lane == 63) { edge[P][1][wv][0] = y0[3]; edge[P][1][wv][1] = y1[3]; } \
    lv0 = __shfl(y0[3], (lane + 63) & 63);                                    \
    lv1 = __shfl(y1[3], (lane + 63) & 63);                                    \
    rv0 = __shfl(y0[0], (lane + 1) & 63);                                     \
    rv1 = __shfl(y1[0], (lane + 1) & 63);                                     \
    asm volatile("s_waitcnt lgkmcnt(0)" ::: "memory");                        \
    __builtin_amdgcn_s_barrier();                                             \
    if (lane == 0)  { lv0 = edge[P][1][(wv + 3) & 3][0]; lv1 = edge[P][1][(wv + 3) & 3][1]; } \
    if (lane == 63) { rv0 = edge[P][0][(wv + 1) & 3][0]; rv1 = edge[P][0][(wv + 1) & 3][1]; } \
  } while (0)

#define STEP(P, U0V, U1V) do {                                                \
    float h0[6], h1[6];                                                       \
    h0[0]=lv0; h0[1]=y0[0]; h0[2]=y0[1]; h0[3]=y0[2]; h0[4]=y0[3]; h0[5]=rv0; \
    h1[0]=lv1; h1[1]=y1[0]; h1[2]=y1[1]; h1[3]=y1[2]; h1[4]=y1[3]; h1[5]=rv1; \
    const float u0a[4] = {(U0V).x, (U0V).y, (U0V).z, (U0V).w};                \
    const float u1a[4] = {(U1V).x, (U1V).y, (U1V).z, (U1V).w};                \
    _Pragma("unroll")                                                         \
    for (int j = 0; j < 4; ++j) {                                             \
      f32x2 acc = BP[j];                                                      \
      f32x2 h;                                                                \
      h = (f32x2){h0[j],   h0[j]};   acc = __builtin_elementwise_fma(WP0[j*3+0], h, acc); \
      h = (f32x2){h0[j+1], h0[j+1]}; acc = __builtin_elementwise_fma(WP0[j*3+1], h, acc); \
      h = (f32x2){h0[j+2], h0[j+2]}; acc = __builtin_elementwise_fma(WP0[j*3+2], h, acc); \
      h = (f32x2){h1[j],   h1[j]};   acc = __builtin_elementwise_fma(WP1[j*3+0], h, acc); \
      h = (f32x2){h1[j+1], h1[j+1]}; acc = __builtin_elementwise_fma(WP1[j*3+1], h, acc); \
      h = (f32x2){h1[j+2], h1[j+2]}; acc = __builtin_elementwise_fma(WP1[j*3+2], h, acc); \
      acc += (f32x2){u0a[j], u1a[j]};                                         \
      f32x2 xx = acc * 2.88539008177792681f;  /* 2*log2(e): tanh=1-2/(2^xx+1) */ \
      float e0 = __builtin_amdgcn_exp2f(xx.x);                                \
      float e1 = __builtin_amdgcn_exp2f(xx.y);                                \
      y0[j] = fmaf(-2.0f, __builtin_amdgcn_rcpf(e0 + 1.0f), 1.0f);            \
      y1[j] = fmaf(-2.0f, __builtin_amdgcn_rcpf(e1 + 1.0f), 1.0f);            \
    }                                                                         \
    EXCH(P);                                                                  \
  } while (0)

    EXCH(1);   // initial halo

    const float* Ub = Ur + (size_t)b * NJ + n0;
#define LD(S, T) do { const size_t o = (size_t)(T) * ((size_t)NB * NJ);       \
    S##0 = *(const float4*)(Ub + o); S##1 = *(const float4*)(Ub + o + NH); } while (0)

    float4 pA0,pA1,pB0,pB1,pC0,pC1,pD0,pD1,pE0,pE1,pF0,pF1,pG0,pG1,pH0,pH1;
    LD(pA,0); LD(pB,1); LD(pC,2); LD(pD,3); LD(pE,4); LD(pF,5); LD(pG,6); LD(pH,7);

    for (int t = 0; t < T_c; t += 8) {
      STEP(0, pA0, pA1); if (t +  8 < T_c) LD(pA, t +  8);
      STEP(1, pB0, pB1); if (t +  9 < T_c) LD(pB, t +  9);
      STEP(0, pC0, pC1); if (t + 10 < T_c) LD(pC, t + 10);
      STEP(1, pD0, pD1); if (t + 11 < T_c) LD(pD, t + 11);
      STEP(0, pE0, pE1); if (t + 12 < T_c) LD(pE, t + 12);
      STEP(1, pF0, pF1); if (t + 13 < T_c) LD(pF, t + 13);
      STEP(0, pG0, pG1); if (t + 14 < T_c) LD(pG, t + 14);
      STEP(1, pH0, pH1); if (t + 15 < T_c) LD(pH, t + 15);
    }
#undef LD
#undef STEP
#undef EXCH

    if (flags & 2) {
      float p[10];
      #pragma unroll
      for (int r = 0; r < 10; ++r) {
        float4 ra = *(const float4*)(Rw + (size_t)r * NJ + n0);
        float4 rb = *(const float4*)(Rw + (size_t)r * NJ + NH + n0);
        p[r] = y0[0]*ra.x + y0[1]*ra.y + y0[2]*ra.z + y0[3]*ra.w
             + y1[0]*rb.x + y1[1]*rb.y + y1[2]*rb.z + y1[3]*rb.w;
      }
      #pragma unroll
      for (int r = 0; r < 10; ++r) {
        #pragma unroll
        for (int off = 32; off > 0; off >>= 1)
          p[r] += __shfl_down(p[r], off);
      }
      __syncthreads();
      if (lane == 0) {
        #pragma unroll
        for (int r = 0; r < 10; ++r) red[wv][r] = p[r];
      }
      __syncthreads();
      if (tid < 10)
        out[blockIdx.x * 10 + tid] = red[0][tid] + red[1][tid] + red[2][tid] + red[3][tid] + Rb[tid];
    } else {
      *(float4*)(state + (size_t)b * NJ + n0)      = make_float4(y0[0], y0[1], y0[2], y0[3]);
      *(float4*)(state + (size_t)b * NJ + NH + n0) = make_float4(y1[0], y1[1], y1[2], y1[3]);
    }
  } else {
    // ================= GEMM (chunk i+1) =================
    const int gb = blockIdx.x - nrec;
    const int ts = gb >> 2;          // timestep within chunk
    const int q  = gb & 3;           // 512-col quarter
    const int l  = threadIdx.x & 63;
    const int lr = l & 15;
    const int lk = l >> 4;
    const long m0 = (long)ts * 128 + (threadIdx.x >> 6) * 32;
    const int jb = q * (NJ / 4);

    // x fragments from pre-split bf16: lane holds x[m0+ms*16+lr][lk*8+e]
    short8 xh[2][4], xl[2][4];
    #pragma unroll
    for (int ms = 0; ms < 2; ++ms) {
      const size_t base = (size_t)(m0 + ms * 16 + lr) * NI + lk * 8;
      #pragma unroll
      for (int kk = 0; kk < 4; ++kk) {
        xh[ms][kk] = *(const short8*)(xhi + base + kk * 32);
        xl[ms][kk] = *(const short8*)(xlo + base + kk * 32);
      }
    }

#define LOADW(WH, WL, J0) do {                                                \
    const size_t wo = (size_t)((J0) + lr) * NI + lk * 8;                      \
    WH[0] = *(const short8*)(Whi + wo);       WH[1] = *(const short8*)(Whi + wo + 32); \
    WH[2] = *(const short8*)(Whi + wo + 64);  WH[3] = *(const short8*)(Whi + wo + 96); \
    WL[0] = *(const short8*)(Wlo + wo);       WL[1] = *(const short8*)(Wlo + wo + 32); \
    WL[2] = *(const short8*)(Wlo + wo + 64);  WL[3] = *(const short8*)(Wlo + wo + 96); \
  } while (0)

#define COMPUTE(WH, WL, J0) do {                                              \
    f32x4 acc0 = {0.f, 0.f, 0.f, 0.f};                                        \
    f32x4 acc1 = {0.f, 0.f, 0.f, 0.f};                                        \
    _Pragma("unroll")                                                         \
    for (int kk = 0; kk < 4; ++kk) {                                          \
      acc0 = MFMA(WH[kk], xh[0][kk], acc0, 0, 0, 0);                          \
      acc0 = MFMA(WH[kk], xl[0][kk], acc0, 0, 0, 0);                          \
      acc0 = MFMA(WL[kk], xh[0][kk], acc0, 0, 0, 0);                          \
      acc1 = MFMA(WH[kk], xh[1][kk], acc1, 0, 0, 0);                          \
      acc1 = MFMA(WH[kk], xl[1][kk], acc1, 0, 0, 0);                          \
      acc1 = MFMA(WL[kk], xh[1][kk], acc1, 0, 0, 0);                          \
    }                                                                         \
    const float4 b4 = *(const float4*)(Wxb + (J0) + lk * 4);                  \
    float4 o0 = make_float4(acc0[0] + b4.x, acc0[1] + b4.y, acc0[2] + b4.z, acc0[3] + b4.w); \
    float4 o1 = make_float4(acc1[0] + b4.x, acc1[1] + b4.y, acc1[2] + b4.z, acc1[3] + b4.w); \
    *(float4*)(Uw + (m0 + lr) * NJ + (J0) + lk * 4)        = o0;              \
    *(float4*)(Uw + (m0 + 16 + lr) * NJ + (J0) + lk * 4)   = o1;              \
  } while (0)

    short8 whA[4], wlA[4], whB[4], wlB[4];
    LOADW(whA, wlA, jb);
    for (int s = 0; s < 32; s += 2) {
      const int j0 = jb + s * 16;
      LOADW(whB, wlB, j0 + 16);
      COMPUTE(whA, wlA, j0);
      if (s + 2 < 32) LOADW(whA, wlA, j0 + 32);
      COMPUTE(whB, wlB, j0 + 16);
    }
#undef LOADW
#undef COMPUTE
  }
}

// ---- fallback (tiny ws): fully fused slow path ----
__global__ __launch_bounds__(1024) void recur_fb(
    const float* __restrict__ x,
    const float* __restrict__ Wxw, const float* __restrict__ Wxb,
    const float* __restrict__ Wyw, const float* __restrict__ Wyb,
    const float* __restrict__ Rw,  const float* __restrict__ Rb,
    float* __restrict__ out)
{
  const int b = blockIdx.x;
  const int n = threadIdx.x;
  __shared__ float2 h2[2][NH];
  __shared__ float  xs[NI];
  __shared__ float  red[16][10];

  const float w000 = Wyw[(size_t)n*3+0],        w001 = Wyw[(size_t)n*3+1],        w002 = Wyw[(size_t)n*3+2];
  const float w010 = Wyw[(size_t)(NH+n)*3+0],   w011 = Wyw[(size_t)(NH+n)*3+1],   w012 = Wyw[(size_t)(NH+n)*3+2];
  const float w100 = Wyw[(size_t)(2*NH+n)*3+0], w101 = Wyw[(size_t)(2*NH+n)*3+1], w102 = Wyw[(size_t)(2*NH+n)*3+2];
  const float w110 = Wyw[(size_t)(3*NH+n)*3+0], w111 = Wyw[(size_t)(3*NH+n)*3+1], w112 = Wyw[(size_t)(3*NH+n)*3+2];
  const float bias0 = Wyb[n], bias1 = Wyb[NH + n];
  const int nm1 = (n + NH - 1) & (NH - 1);
  const int np1 = (n + 1) & (NH - 1);

  float c0 = 0.f, c1 = 0.f;
  h2[0][n] = make_float2(c0, c1);
  __syncthreads();

  int cur = 0;
  for (int t = 0; t < T_TOT; ++t) {
    if (n < NI) xs[n] = x[(size_t)t * NB * NI + (size_t)b * NI + n];
    __syncthreads();
    float u0 = Wxb[n], u1 = Wxb[NH + n];
    const float* wr0 = Wxw + (size_t)n * NI;
    const float* wr1 = Wxw + (size_t)(NH + n) * NI;
    #pragma unroll 8
    for (int i = 0; i < NI; ++i) {
      u0 = fmaf(xs[i], wr0[i], u0);
      u1 = fmaf(xs[i], wr1[i], u1);
    }
    float2 Lv = h2[cur][nm1];
    float2 Rv = h2[cur][np1];
    float loc0 = bias0 + w000*Lv.x + w001*c0 + w002*Rv.x + w010*Lv.y + w011*c1 + w012*Rv.y;
    float loc1 = bias1 + w100*Lv.x + w101*c0 + w102*Rv.x + w110*Lv.y + w111*c1 + w112*Rv.y;
    float e0 = __expf(2.0f * (u0 + loc0));
    float e1 = __expf(2.0f * (u1 + loc1));
    c0 = 1.0f - __fdividef(2.0f, e0 + 1.0f);
    c1 = 1.0f - __fdividef(2.0f, e1 + 1.0f);
    h2[cur ^ 1][n] = make_float2(c0, c1);
    cur ^= 1;
    __syncthreads();
  }

  float p[10];
  #pragma unroll
  for (int r = 0; r < 10; ++r)
    p[r] = c0 * Rw[(size_t)r * NJ + n] + c1 * Rw[(size_t)r * NJ + NH + n];
  #pragma unroll
  for (int r = 0; r < 10; ++r) {
    #pragma unroll
    for (int off = 32; off > 0; off >>= 1)
      p[r] += __shfl_down(p[r], off);
  }
  const int wv = n >> 6;
  if ((n & 63) == 0) {
    #pragma unroll
    for (int r = 0; r < 10; ++r) red[wv][r] = p[r];
  }
  __syncthreads();
  if (n < 10) {
    float s = 0.f;
    #pragma unroll
    for (int k = 0; k < 16; ++k) s += red[k][n];
    out[b * 10 + n] = s + Rb[n];
  }
}

extern "C" void kernel_launch(void* const* d_in, const int* in_sizes, int n_in,
                              void* d_out, int out_size, void* d_ws, size_t ws_size,
                              hipStream_t stream) {
  const float* x   = (const float*)d_in[0];
  const float* Wxw = (const float*)d_in[1];
  const float* Wxb = (const float*)d_in[2];
  const float* Wyw = (const float*)d_in[3];
  const float* Wyb = (const float*)d_in[4];
  const float* Rw  = (const float*)d_in[5];
  const float* Rb  = (const float*)d_in[6];
  float* out = (float*)d_out;

  const size_t w1_bytes = (size_t)NJ * NI * 2;        // 512 KB bf16 Wx half
  const size_t x1_bytes = (size_t)T_TOT * NB * NI * 2; // 16.8 MB bf16 x half
  const size_t st_bytes = (size_t)NB * NJ * 4;        // 1 MB carry state
  const size_t ut_bytes = (size_t)NB * NJ * 4;        // 1 MB per timestep of U

  char* p = (char*)d_ws;
  unsigned short* Whi = (unsigned short*)p;              p += w1_bytes;
  unsigned short* Wlo = (unsigned short*)p;              p += w1_bytes;
  unsigned short* Xhi = (unsigned short*)p;              p += x1_bytes;
  unsigned short* Xlo = (unsigned short*)p;              p += x1_bytes;
  float* state = (float*)p;                              p += st_bytes;
  float* U     = (float*)p;
  const size_t fixed = (size_t)(p - (char*)d_ws);

  long Tc = 64;
  while (Tc >= 8 && fixed + 2 * (size_t)Tc * ut_bytes > ws_size) Tc >>= 1;

  if (Tc >= 8) {
    const int NC = T_TOT / (int)Tc;
    const size_t uhalf = (size_t)Tc * NB * NJ;   // elements per U half
    cvt_wx<<<64, 256, 0, stream>>>(Wxw, Whi, Wlo);
    cvt_x<<<1024, 256, 0, stream>>>(x, Xhi, Xlo);
    // prime: gemm chunk 0 into half 0 (no recur blocks)
    fused<<<(int)Tc * 4, 256, 0, stream>>>(
        Xhi, Xlo, Whi, Wlo, Wxb, U, nullptr,
        Wyw, Wyb, Rw, Rb, state, out, (int)Tc, 0, 0);
    for (int i = 0; i < NC; ++i) {
      const int flags = (i == 0 ? 1 : 0) | (i == NC - 1 ? 2 : 0);
      const int ng = (i + 1 < NC) ? (int)Tc * 4 : 0;
      const size_t xo = (size_t)(i + 1) * Tc * NB * NI;
      fused<<<128 + ng, 256, 0, stream>>>(
          Xhi + (ng ? xo : 0), Xlo + (ng ? xo : 0), Whi, Wlo, Wxb,
          U + ((size_t)((i + 1) & 1)) * uhalf,       // write half (chunk i+1)
          U + ((size_t)(i & 1)) * uhalf,             // read half (chunk i)
          Wyw, Wyb, Rw, Rb, state, out, (int)Tc, 128, flags);
    }
  } else {
    recur_fb<<<NB, 1024, 0, stream>>>(x, Wxw, Wxb, Wyw, Wyb, Rw, Rb, out);
  }
}